// Round 1
// baseline (55.083 us; speedup 1.0000x reference)
//
#include <hip/hip_runtime.h>
#include <hip/hip_bf16.h>

// Problem: x1,x2 are fp32 [2,4] -> reshaped [4,2] (a,b).
// Outputs concatenated flat (96 fp32 total):
//   [0,16)  x3 = a @ b.T          (4x4)
//   [16,32) x4 = x3.T             (4x4)
//   [32,40) v1 = a                (4x2)  == x1 flat
//   [40,48) v2 = a.T              (2x4)
//   [48,52) v3 = a.T @ a          (2x2)
//   [52,68) v4 = a @ a.T          (4x4)
//   [68,72) v5 = b.T @ a          (2x2)
//   [72,88) v6 = a @ b.T          (4x4)  == x3
//   [88,96) v7 = a.T              (2x4)  == v2
// a(r,c) = x1[2r+c], b(r,c) = x2[2r+c].
// One block, 128 threads (2 waves), thread t computes out[t]. Launch-bound.

__global__ void Model_39676907882930_kernel(const float* __restrict__ x1,
                                            const float* __restrict__ x2,
                                            float* __restrict__ out) {
    const int t = threadIdx.x;
    if (t >= 96) return;

    float v;
    if (t < 16) {
        // x3(i,j) = sum_k a(i,k)*b(j,k), k in {0,1}
        const int i = t >> 2, j = t & 3;
        v = x1[2 * i] * x2[2 * j] + x1[2 * i + 1] * x2[2 * j + 1];
    } else if (t < 32) {
        // x4(i,j) = x3(j,i)
        const int u = t - 16;
        const int i = u >> 2, j = u & 3;
        v = x1[2 * j] * x2[2 * i] + x1[2 * j + 1] * x2[2 * i + 1];
    } else if (t < 40) {
        // v1 = a, row-major flat == x1 flat
        v = x1[t - 32];
    } else if (t < 48) {
        // v2(i,j) = a(j,i) = x1[2j+i]; i in [0,2), j in [0,4)
        const int u = t - 40;
        const int i = u >> 2, j = u & 3;
        v = x1[2 * j + i];
    } else if (t < 52) {
        // v3(i,j) = sum_k a(k,i)*a(k,j), k in [0,4)
        const int u = t - 48;
        const int i = u >> 1, j = u & 1;
        v = 0.0f;
        #pragma unroll
        for (int k = 0; k < 4; ++k) v += x1[2 * k + i] * x1[2 * k + j];
    } else if (t < 68) {
        // v4(i,j) = sum_k a(i,k)*a(j,k), k in {0,1}
        const int u = t - 52;
        const int i = u >> 2, j = u & 3;
        v = x1[2 * i] * x1[2 * j] + x1[2 * i + 1] * x1[2 * j + 1];
    } else if (t < 72) {
        // v5(i,j) = sum_k b(k,i)*a(k,j), k in [0,4)
        const int u = t - 68;
        const int i = u >> 1, j = u & 1;
        v = 0.0f;
        #pragma unroll
        for (int k = 0; k < 4; ++k) v += x2[2 * k + i] * x1[2 * k + j];
    } else if (t < 88) {
        // v6 = x3
        const int u = t - 72;
        const int i = u >> 2, j = u & 3;
        v = x1[2 * i] * x2[2 * j] + x1[2 * i + 1] * x2[2 * j + 1];
    } else {
        // v7 = v2
        const int u = t - 88;
        const int i = u >> 2, j = u & 3;
        v = x1[2 * j + i];
    }
    out[t] = v;
}

extern "C" void kernel_launch(void* const* d_in, const int* in_sizes, int n_in,
                              void* d_out, int out_size, void* d_ws, size_t ws_size,
                              hipStream_t stream) {
    const float* x1 = (const float*)d_in[0];
    const float* x2 = (const float*)d_in[1];
    float* out = (float*)d_out;
    Model_39676907882930_kernel<<<1, 128, 0, stream>>>(x1, x2, out);
}